// Round 7
// baseline (4945.341 us; speedup 1.0000x reference)
//
#include <hip/hip_runtime.h>
#include <hip/hip_bf16.h>

// KWSNet: conv1d+relu -> 2x GRU (fwd-scan, two weight sets) -> sliding mean -> linear(2)
// B=64, M=80, T=2000, C=H=256, K=5; Tc=1996, W=96, Tout=1901, out (1901,1,64,2) fp32.
//
// Chunked pipeline (8 x <=250 steps), per chunk: conv -> proj (fp16 MFMA) ->
// persistent GRU scan. Scan: 1024 threads/block, thread (i=tid&255, q=tid>>8)
// holds W_hh rows {i,i+256,i+512} cols [64q,64q+64) as 24 NAMED h8_t SSA vars
// (96 VGPRs) -- fits the 128-VGPR budget the backend insists on for large
// blocks (R4-R6: every attempt to raise the budget via launch_bounds /
// amdgpu_waves_per_eu left VGPR_Count=128 and spilled 44 MB to scratch).
// K-partials combined via LDS parr; h broadcast via LDS hbuf.

#define TT    2000
#define TC    1996
#define NB    64
#define MCH   80
#define NH    256
#define NN    1536           // 2 * 3H
#define TOUT  1901
#define TCH   250            // chunk length (last chunk = 246)
#define NCHK  8
#define CROWS (TCH * NB)     // 16000 rows per chunk

typedef _Float16 h2_t __attribute__((ext_vector_type(2)));
typedef _Float16 h8_t __attribute__((ext_vector_type(8)));
typedef float    f4_t __attribute__((ext_vector_type(4)));

// ---------------- workspace layout (bytes), total ~59.7 MB ----------------
#define OFF_SEQC ((size_t)0)            // fp16 [CROWS][256]     = 8,192,000
#define OFF_XG   ((size_t)8192000)      // fp16 [2][CROWS][768]  = 49,152,000
#define OFF_WT   ((size_t)57344000)     // fp32 [400][256]       = 409,600
#define OFF_WCAT ((size_t)57753600)     // fp16 [1536][256]      = 786,432
#define OFF_PSUM ((size_t)58540032)     // fp32 [TC][64][2]      = 1,021,952
#define OFF_HST  ((size_t)59561984)     // fp32 [128][256]       = 131,072

// ---------------- prep: transpose conv_w, fp16 w_ih concat, zero psum ----------------
__global__ void prep_kernel(const float* __restrict__ conv_w,
                            const float* __restrict__ wihf,
                            const float* __restrict__ wihr,
                            float* __restrict__ wT,
                            _Float16* __restrict__ wcat,
                            float* __restrict__ psum) {
    int idx = blockIdx.x * 256 + threadIdx.x;
    if (idx < 400 * 256) {
        int c = idx & 255, mk = idx >> 8;
        wT[idx] = conv_w[c * 400 + mk];
    }
    int i2 = idx - 400 * 256;
    if (i2 >= 0 && i2 < NN * 256) {
        int k = i2 & 255, n = i2 >> 8;
        float v = (n < 768) ? wihf[n * 256 + k] : wihr[(n - 768) * 256 + k];
        wcat[i2] = (_Float16)v;
    }
    int i3 = idx - (400 * 256 + NN * 256);
    if (i3 >= 0 && i3 < TC * 64 * 2) psum[i3] = 0.f;
}

// ---------------- conv1d(valid,K=5)+bias+relu -> seqc fp16 [t_local*64+b][c] ----------------
__global__ __launch_bounds__(256, 2)
void conv_kernel(const float* __restrict__ x, const float* __restrict__ wT,
                 const float* __restrict__ conv_b, _Float16* __restrict__ seqc,
                 int t_base, int t_len) {
    __shared__ float xs[MCH][68];
    int tile = blockIdx.x;           // 0..3
    int b    = blockIdx.y;           // 0..63
    int tid  = threadIdx.x;
    for (int idx = tid; idx < MCH * 68; idx += 256) {
        int m = idx / 68, i = idx - m * 68;
        int tt = t_base + tile * 64 + i;
        xs[m][i] = (tt < TT) ? x[(size_t)b * (MCH * TT) + m * TT + tt] : 0.f;
    }
    __syncthreads();
    int lane = tid & 63, tg = tid >> 6;   // wave tg: t-range [tg*16, tg*16+16)
    float acc[4][16];
#pragma unroll
    for (int cq = 0; cq < 4; ++cq)
#pragma unroll
        for (int t = 0; t < 16; ++t) acc[cq][t] = 0.f;

    for (int m = 0; m < MCH; ++m) {
        float xr_[20];
#pragma unroll
        for (int q = 0; q < 5; ++q) {
            float4 v = *(const float4*)&xs[m][tg * 16 + q * 4];
            xr_[q * 4 + 0] = v.x; xr_[q * 4 + 1] = v.y;
            xr_[q * 4 + 2] = v.z; xr_[q * 4 + 3] = v.w;
        }
#pragma unroll
        for (int cq = 0; cq < 4; ++cq) {
            int c = lane + cq * 64;
            const float* wp = wT + (size_t)(m * 5) * 256 + c;
            float w0_ = wp[0], w1_ = wp[256], w2_ = wp[512], w3_ = wp[768], w4_ = wp[1024];
#pragma unroll
            for (int t = 0; t < 16; ++t)
                acc[cq][t] += w0_ * xr_[t] + w1_ * xr_[t + 1] + w2_ * xr_[t + 2]
                            + w3_ * xr_[t + 3] + w4_ * xr_[t + 4];
        }
    }
#pragma unroll
    for (int cq = 0; cq < 4; ++cq) {
        int c = lane + cq * 64;
        float cb = conv_b[c];
        for (int t = 0; t < 16; ++t) {
            int tl = tile * 64 + tg * 16 + t;     // t within chunk
            if (tl < t_len) {
                float v = acc[cq][t] + cb;
                v = v > 0.f ? v : 0.f;
                seqc[((size_t)tl * 64 + b) * 256 + c] = (_Float16)v;
            }
        }
    }
}

// ---------------- proj: xg[d][row][j] = seqc @ w_ih^T + b_ih (fp16 MFMA 16x16x32) ----------------
__global__ __launch_bounds__(256, 2)
void proj_kernel(const _Float16* __restrict__ seqc, const _Float16* __restrict__ wcat,
                 const float* __restrict__ bihf, const float* __restrict__ bihr,
                 _Float16* __restrict__ xg) {
    __shared__ __align__(16) _Float16 As[128][72];
    __shared__ __align__(16) _Float16 Bs[128][72];
    int row0 = blockIdx.x * 128;     // up to 125 tiles
    int n0   = blockIdx.y * 128;     // 12 tiles
    int tid  = threadIdx.x;
    int lane = tid & 63, wv = tid >> 6;
    int wr = wv >> 1, wc = wv & 1;                 // 2x2 waves of 64x64
    int fm = lane & 15, fq = lane >> 4;            // fragment index, quad
    f4_t acc[4][4];
#pragma unroll
    for (int mt = 0; mt < 4; ++mt)
#pragma unroll
        for (int nt = 0; nt < 4; ++nt) acc[mt][nt] = (f4_t){0.f, 0.f, 0.f, 0.f};

    int r = tid >> 1, part = tid & 1;
    for (int kc = 0; kc < 4; ++kc) {
        const uint4* srcA = (const uint4*)&seqc[(size_t)(row0 + r) * 256 + kc * 64 + part * 32];
        const uint4* srcB = (const uint4*)&wcat[(size_t)(n0 + r) * 256 + kc * 64 + part * 32];
        uint4* dstA = (uint4*)&As[r][part * 32];
        uint4* dstB = (uint4*)&Bs[r][part * 32];
        dstA[0] = srcA[0]; dstA[1] = srcA[1]; dstA[2] = srcA[2]; dstA[3] = srcA[3];
        dstB[0] = srcB[0]; dstB[1] = srcB[1]; dstB[2] = srcB[2]; dstB[3] = srcB[3];
        __syncthreads();
#pragma unroll
        for (int ks = 0; ks < 64; ks += 32) {
            h8_t af[4], bf[4];
#pragma unroll
            for (int mt = 0; mt < 4; ++mt)
                af[mt] = *(const h8_t*)&As[wr * 64 + mt * 16 + fm][ks + fq * 8];
#pragma unroll
            for (int nt = 0; nt < 4; ++nt)
                bf[nt] = *(const h8_t*)&Bs[wc * 64 + nt * 16 + fm][ks + fq * 8];
#pragma unroll
            for (int mt = 0; mt < 4; ++mt)
#pragma unroll
                for (int nt = 0; nt < 4; ++nt)
                    acc[mt][nt] = __builtin_amdgcn_mfma_f32_16x16x32_f16(
                        af[mt], bf[nt], acc[mt][nt], 0, 0, 0);
        }
        __syncthreads();
    }
    // epilogue: C col = lane&15 (n-dim), row = (lane>>4)*4 + reg (m-dim)
#pragma unroll
    for (int nt = 0; nt < 4; ++nt) {
        int col = n0 + wc * 64 + nt * 16 + fm;
        int d = (col < 768) ? 0 : 1;
        int j = col - d * 768;
        float bias = d ? bihr[j] : bihf[j];
        size_t obase = (size_t)d * CROWS * 768 + j;
#pragma unroll
        for (int mt = 0; mt < 4; ++mt) {
            int row = row0 + wr * 64 + mt * 16 + fq * 4;
#pragma unroll
            for (int rr = 0; rr < 4; ++rr)
                xg[obase + (size_t)(row + rr) * 768] = (_Float16)(acc[mt][nt][rr] + bias);
        }
    }
}

// ---------------- persistent GRU scan chunk: 1 block per (direction, batch) chain ----------------
// 1024 threads; thread (i=tid&255, q=tid>>8) holds rows {i,i+256,i+512} cols
// [64q,64q+64) as 24 named h8_t (96 VGPRs). q>0 partials -> LDS; q0 combines,
// computes gates, writes hbuf (double-buffered), emits clf partials via atomics.

#define LDROW8(W, P) do {                                                     \
    float4 _a = *(const float4*)(P); float4 _b = *(const float4*)((P) + 4);   \
    W = (h8_t){(_Float16)_a.x, (_Float16)_a.y, (_Float16)_a.z, (_Float16)_a.w,\
               (_Float16)_b.x, (_Float16)_b.y, (_Float16)_b.z, (_Float16)_b.w};\
} while (0)

#define DOT8(ACC, WV, HV) do {                                                \
    uint4 _wc = __builtin_bit_cast(uint4, WV);                                \
    ACC = __builtin_amdgcn_fdot2(__builtin_bit_cast(h2_t, _wc.x),             \
                                 __builtin_bit_cast(h2_t, (HV).x), ACC, false);\
    ACC = __builtin_amdgcn_fdot2(__builtin_bit_cast(h2_t, _wc.y),             \
                                 __builtin_bit_cast(h2_t, (HV).y), ACC, false);\
    ACC = __builtin_amdgcn_fdot2(__builtin_bit_cast(h2_t, _wc.z),             \
                                 __builtin_bit_cast(h2_t, (HV).z), ACC, false);\
    ACC = __builtin_amdgcn_fdot2(__builtin_bit_cast(h2_t, _wc.w),             \
                                 __builtin_bit_cast(h2_t, (HV).w), ACC, false);\
} while (0)

__global__ __launch_bounds__(1024)
void scan_kernel(const _Float16* __restrict__ xg,
                 const float* __restrict__ whhf, const float* __restrict__ whhr,
                 const float* __restrict__ bhhf, const float* __restrict__ bhhr,
                 const float* __restrict__ clf_w, float* __restrict__ psum,
                 float* __restrict__ hstate, int t0, int len, int first) {
    int blk = blockIdx.x;
    int d = blk >> 6, b = blk & 63;
    int tid = threadIdx.x;
    int i = tid & 255, q = tid >> 8;     // q is wave-uniform (waves 0-3:q0 .. 12-15:q3)
    const float* whh = d ? whhr : whhf;
    const float* bhh = d ? bhhr : bhhf;

    const float* w0p = whh + (size_t)i * 256 + q * 64;
    const float* w1p = whh + (size_t)(i + 256) * 256 + q * 64;
    const float* w2p = whh + (size_t)(i + 512) * 256 + q * 64;

    h8_t w00, w01, w02, w03, w04, w05, w06, w07;
    h8_t w10, w11, w12, w13, w14, w15, w16, w17;
    h8_t w20, w21, w22, w23, w24, w25, w26, w27;
    LDROW8(w00, w0p +  0); LDROW8(w01, w0p +  8); LDROW8(w02, w0p + 16); LDROW8(w03, w0p + 24);
    LDROW8(w04, w0p + 32); LDROW8(w05, w0p + 40); LDROW8(w06, w0p + 48); LDROW8(w07, w0p + 56);
    LDROW8(w10, w1p +  0); LDROW8(w11, w1p +  8); LDROW8(w12, w1p + 16); LDROW8(w13, w1p + 24);
    LDROW8(w14, w1p + 32); LDROW8(w15, w1p + 40); LDROW8(w16, w1p + 48); LDROW8(w17, w1p + 56);
    LDROW8(w20, w2p +  0); LDROW8(w21, w2p +  8); LDROW8(w22, w2p + 16); LDROW8(w23, w2p + 24);
    LDROW8(w24, w2p + 32); LDROW8(w25, w2p + 40); LDROW8(w26, w2p + 48); LDROW8(w27, w2p + 56);

    float bhr = 0.f, bhz = 0.f, bhn = 0.f, cw0 = 0.f, cw1 = 0.f, h = 0.f;
    if (q == 0) {
        bhr = bhh[i]; bhz = bhh[256 + i]; bhn = bhh[512 + i];
        cw0 = clf_w[d * 256 + i];          // clf_w[0][d*256+i]
        cw1 = clf_w[512 + d * 256 + i];    // clf_w[1][d*256+i]
        h = first ? 0.f : hstate[(size_t)blk * 256 + i];
    }

    __shared__ __align__(16) _Float16 hbuf[2][256];
    __shared__ float parr[3][4][256];
    if (q == 0) hbuf[0][i] = (_Float16)h;
    __syncthreads();

    const _Float16* xgp = xg + (size_t)d * CROWS * 768 + (size_t)b * 768 + i;
    int cur = 0;
    for (int t = 0; t < len; ++t) {
        float xr = 0.f, xz = 0.f, xn = 0.f;
        if (q == 0) {
            xr = (float)xgp[0];
            xz = (float)xgp[256];
            xn = (float)xgp[512];
        }
        xgp += (size_t)64 * 768;

        // all lanes of a wave read the same address -> LDS broadcast, conflict-free
        const uint4* hp = (const uint4*)&hbuf[cur][q * 64];
        float a0 = 0.f, a1 = 0.f, a2 = 0.f;
        uint4 hv;
        hv = hp[0]; DOT8(a0, w00, hv); DOT8(a1, w10, hv); DOT8(a2, w20, hv);
        hv = hp[1]; DOT8(a0, w01, hv); DOT8(a1, w11, hv); DOT8(a2, w21, hv);
        hv = hp[2]; DOT8(a0, w02, hv); DOT8(a1, w12, hv); DOT8(a2, w22, hv);
        hv = hp[3]; DOT8(a0, w03, hv); DOT8(a1, w13, hv); DOT8(a2, w23, hv);
        hv = hp[4]; DOT8(a0, w04, hv); DOT8(a1, w14, hv); DOT8(a2, w24, hv);
        hv = hp[5]; DOT8(a0, w05, hv); DOT8(a1, w15, hv); DOT8(a2, w25, hv);
        hv = hp[6]; DOT8(a0, w06, hv); DOT8(a1, w16, hv); DOT8(a2, w26, hv);
        hv = hp[7]; DOT8(a0, w07, hv); DOT8(a1, w17, hv); DOT8(a2, w27, hv);

        if (q) {
            parr[0][q][i] = a0; parr[1][q][i] = a1; parr[2][q][i] = a2;
        }
        __syncthreads();
        if (q == 0) {
            float hr = a0 + parr[0][1][i] + parr[0][2][i] + parr[0][3][i] + bhr;
            float hz = a1 + parr[1][1][i] + parr[1][2][i] + parr[1][3][i] + bhz;
            float hn = a2 + parr[2][1][i] + parr[2][2][i] + parr[2][3][i] + bhn;
            float rg = 1.f / (1.f + __expf(-(xr + hr)));
            float zg = 1.f / (1.f + __expf(-(xz + hz)));
            float xnr = xn + rg * hn;
            float nv = 1.f - 2.f / (__expf(2.f * xnr) + 1.f);   // tanh
            h = (1.f - zg) * nv + zg * h;
            hbuf[cur ^ 1][i] = (_Float16)h;

            float pc0 = cw0 * h, pc1 = cw1 * h;
#pragma unroll
            for (int off = 32; off; off >>= 1) {
                pc0 += __shfl_xor(pc0, off, 64);
                pc1 += __shfl_xor(pc1, off, 64);
            }
            if ((tid & 63) == 0) {
                atomicAdd(&psum[((size_t)(t0 + t) * 64 + b) * 2 + 0], pc0);
                atomicAdd(&psum[((size_t)(t0 + t) * 64 + b) * 2 + 1], pc1);
            }
        }
        __syncthreads();
        cur ^= 1;
    }
    if (q == 0) hstate[(size_t)blk * 256 + i] = h;
}

// ---------------- final: sliding mean over W steps + clf bias ----------------
__global__ void final_kernel(const float* __restrict__ psum, const float* __restrict__ clf_b,
                             const int* __restrict__ win, float* __restrict__ out) {
    int idx = blockIdx.x * 256 + threadIdx.x;
    if (idx >= TOUT * 128) return;
    int c = idx & 1;
    int rem = idx >> 1;
    int b = rem & 63;
    int tau = rem >> 6;
    int W = win[0] - 5 + 1;   // 96
    float s = 0.f;
    for (int j = 0; j < W; ++j)
        s += psum[((size_t)(tau + j) * 64 + b) * 2 + c];
    out[idx] = s / (float)W + clf_b[c];
}

extern "C" void kernel_launch(void* const* d_in, const int* in_sizes, int n_in,
                              void* d_out, int out_size, void* d_ws, size_t ws_size,
                              hipStream_t stream) {
    const float* x      = (const float*)d_in[0];
    const float* conv_w = (const float*)d_in[1];
    const float* conv_b = (const float*)d_in[2];
    const float* w_ih_f = (const float*)d_in[3];
    const float* w_hh_f = (const float*)d_in[4];
    const float* b_ih_f = (const float*)d_in[5];
    const float* b_hh_f = (const float*)d_in[6];
    const float* w_ih_r = (const float*)d_in[7];
    const float* w_hh_r = (const float*)d_in[8];
    const float* b_ih_r = (const float*)d_in[9];
    const float* b_hh_r = (const float*)d_in[10];
    const float* clf_w  = (const float*)d_in[11];
    const float* clf_b  = (const float*)d_in[12];
    const int*   win    = (const int*)d_in[13];
    float* out = (float*)d_out;

    char* ws = (char*)d_ws;
    _Float16* seqc = (_Float16*)(ws + OFF_SEQC);
    _Float16* xg   = (_Float16*)(ws + OFF_XG);
    float*    wT   = (float*)(ws + OFF_WT);
    _Float16* wcat = (_Float16*)(ws + OFF_WCAT);
    float*    psum = (float*)(ws + OFF_PSUM);
    float*    hst  = (float*)(ws + OFF_HST);

    int prep_elems = 400 * 256 + NN * 256 + TC * 64 * 2;
    prep_kernel<<<(prep_elems + 255) / 256, 256, 0, stream>>>(conv_w, w_ih_f, w_ih_r, wT, wcat, psum);

    for (int c = 0; c < NCHK; ++c) {
        int t0  = c * TCH;
        int len = (c == NCHK - 1) ? (TC - t0) : TCH;   // 250 / last 246
        conv_kernel<<<dim3(4, 64), 256, 0, stream>>>(x, wT, conv_b, seqc, t0, len);
        proj_kernel<<<dim3(len * 64 / 128, 12), 256, 0, stream>>>(seqc, wcat, b_ih_f, b_ih_r, xg);
        scan_kernel<<<128, 1024, 0, stream>>>(xg, w_hh_f, w_hh_r, b_hh_f, b_hh_r,
                                              clf_w, psum, hst, t0, len, c == 0);
    }
    final_kernel<<<(TOUT * 128 + 255) / 256, 256, 0, stream>>>(psum, clf_b, win, out);
}

// Round 8
// 4353.493 us; speedup vs baseline: 1.1359x; 1.1359x over previous
//
#include <hip/hip_runtime.h>
#include <hip/hip_bf16.h>

// KWSNet: conv1d+relu -> 2x GRU (fwd-scan, two weight sets) -> sliding mean -> linear(2)
// B=64, M=80, T=2000, C=H=256, K=5; Tc=1996, W=96, Tout=1901, out (1901,1,64,2) fp32.
//
// Chunked pipeline (8 x <=250 steps), per chunk: conv -> proj (fp16 MFMA) ->
// persistent GRU scan. Scan: 512 threads/block, thread (i=tid&255, half=tid>>8)
// holds W_hh rows {i,i+256,i+512} cols [half*128,half*128+128) in 192 VGPRs.
//
// Register-budget law measured R3-R7: the backend targets 2 blocks/CU and
// budgets exactly 65536/B VGPRs (B=block threads): 256/128/64 for B=256/512/
// 1024 -- weights (98304 reg-slots) never fit, spill 44-53 MB to scratch.
// Fix: >80 KB static LDS forces 1 block/CU; the LDS-limited occupancy frees
// the allocator to grant 256 VGPRs for the 8-wave block. Weights then fit.

#define TT    2000
#define TC    1996
#define NB    64
#define MCH   80
#define NH    256
#define NN    1536           // 2 * 3H
#define TOUT  1901
#define TCH   250            // chunk length (last chunk = 246)
#define NCHK  8
#define CROWS (TCH * NB)     // 16000 rows per chunk

typedef _Float16 h2_t __attribute__((ext_vector_type(2)));
typedef _Float16 h8_t __attribute__((ext_vector_type(8)));
typedef float    f4_t __attribute__((ext_vector_type(4)));

// ---------------- workspace layout (bytes), total ~59.7 MB ----------------
#define OFF_SEQC ((size_t)0)            // fp16 [CROWS][256]     = 8,192,000
#define OFF_XG   ((size_t)8192000)      // fp16 [2][CROWS][768]  = 49,152,000
#define OFF_WT   ((size_t)57344000)     // fp32 [400][256]       = 409,600
#define OFF_WCAT ((size_t)57753600)     // fp16 [1536][256]      = 786,432
#define OFF_PSUM ((size_t)58540032)     // fp32 [TC][64][2]      = 1,021,952
#define OFF_HST  ((size_t)59561984)     // fp32 [128][256]       = 131,072

// ---------------- prep: transpose conv_w, fp16 w_ih concat, zero psum ----------------
__global__ void prep_kernel(const float* __restrict__ conv_w,
                            const float* __restrict__ wihf,
                            const float* __restrict__ wihr,
                            float* __restrict__ wT,
                            _Float16* __restrict__ wcat,
                            float* __restrict__ psum) {
    int idx = blockIdx.x * 256 + threadIdx.x;
    if (idx < 400 * 256) {
        int c = idx & 255, mk = idx >> 8;
        wT[idx] = conv_w[c * 400 + mk];
    }
    int i2 = idx - 400 * 256;
    if (i2 >= 0 && i2 < NN * 256) {
        int k = i2 & 255, n = i2 >> 8;
        float v = (n < 768) ? wihf[n * 256 + k] : wihr[(n - 768) * 256 + k];
        wcat[i2] = (_Float16)v;
    }
    int i3 = idx - (400 * 256 + NN * 256);
    if (i3 >= 0 && i3 < TC * 64 * 2) psum[i3] = 0.f;
}

// ---------------- conv1d(valid,K=5)+bias+relu -> seqc fp16 [t_local*64+b][c] ----------------
__global__ __launch_bounds__(256, 2)
void conv_kernel(const float* __restrict__ x, const float* __restrict__ wT,
                 const float* __restrict__ conv_b, _Float16* __restrict__ seqc,
                 int t_base, int t_len) {
    __shared__ float xs[MCH][68];
    int tile = blockIdx.x;           // 0..3
    int b    = blockIdx.y;           // 0..63
    int tid  = threadIdx.x;
    for (int idx = tid; idx < MCH * 68; idx += 256) {
        int m = idx / 68, i = idx - m * 68;
        int tt = t_base + tile * 64 + i;
        xs[m][i] = (tt < TT) ? x[(size_t)b * (MCH * TT) + m * TT + tt] : 0.f;
    }
    __syncthreads();
    int lane = tid & 63, tg = tid >> 6;   // wave tg: t-range [tg*16, tg*16+16)
    float acc[4][16];
#pragma unroll
    for (int cq = 0; cq < 4; ++cq)
#pragma unroll
        for (int t = 0; t < 16; ++t) acc[cq][t] = 0.f;

    for (int m = 0; m < MCH; ++m) {
        float xr_[20];
#pragma unroll
        for (int q = 0; q < 5; ++q) {
            float4 v = *(const float4*)&xs[m][tg * 16 + q * 4];
            xr_[q * 4 + 0] = v.x; xr_[q * 4 + 1] = v.y;
            xr_[q * 4 + 2] = v.z; xr_[q * 4 + 3] = v.w;
        }
#pragma unroll
        for (int cq = 0; cq < 4; ++cq) {
            int c = lane + cq * 64;
            const float* wp = wT + (size_t)(m * 5) * 256 + c;
            float w0_ = wp[0], w1_ = wp[256], w2_ = wp[512], w3_ = wp[768], w4_ = wp[1024];
#pragma unroll
            for (int t = 0; t < 16; ++t)
                acc[cq][t] += w0_ * xr_[t] + w1_ * xr_[t + 1] + w2_ * xr_[t + 2]
                            + w3_ * xr_[t + 3] + w4_ * xr_[t + 4];
        }
    }
#pragma unroll
    for (int cq = 0; cq < 4; ++cq) {
        int c = lane + cq * 64;
        float cb = conv_b[c];
        for (int t = 0; t < 16; ++t) {
            int tl = tile * 64 + tg * 16 + t;     // t within chunk
            if (tl < t_len) {
                float v = acc[cq][t] + cb;
                v = v > 0.f ? v : 0.f;
                seqc[((size_t)tl * 64 + b) * 256 + c] = (_Float16)v;
            }
        }
    }
}

// ---------------- proj: xg[d][row][j] = seqc @ w_ih^T + b_ih (fp16 MFMA 16x16x32) ----------------
__global__ __launch_bounds__(256, 2)
void proj_kernel(const _Float16* __restrict__ seqc, const _Float16* __restrict__ wcat,
                 const float* __restrict__ bihf, const float* __restrict__ bihr,
                 _Float16* __restrict__ xg) {
    __shared__ __align__(16) _Float16 As[128][72];
    __shared__ __align__(16) _Float16 Bs[128][72];
    int row0 = blockIdx.x * 128;     // up to 125 tiles
    int n0   = blockIdx.y * 128;     // 12 tiles
    int tid  = threadIdx.x;
    int lane = tid & 63, wv = tid >> 6;
    int wr = wv >> 1, wc = wv & 1;                 // 2x2 waves of 64x64
    int fm = lane & 15, fq = lane >> 4;            // fragment index, quad
    f4_t acc[4][4];
#pragma unroll
    for (int mt = 0; mt < 4; ++mt)
#pragma unroll
        for (int nt = 0; nt < 4; ++nt) acc[mt][nt] = (f4_t){0.f, 0.f, 0.f, 0.f};

    int r = tid >> 1, part = tid & 1;
    for (int kc = 0; kc < 4; ++kc) {
        const uint4* srcA = (const uint4*)&seqc[(size_t)(row0 + r) * 256 + kc * 64 + part * 32];
        const uint4* srcB = (const uint4*)&wcat[(size_t)(n0 + r) * 256 + kc * 64 + part * 32];
        uint4* dstA = (uint4*)&As[r][part * 32];
        uint4* dstB = (uint4*)&Bs[r][part * 32];
        dstA[0] = srcA[0]; dstA[1] = srcA[1]; dstA[2] = srcA[2]; dstA[3] = srcA[3];
        dstB[0] = srcB[0]; dstB[1] = srcB[1]; dstB[2] = srcB[2]; dstB[3] = srcB[3];
        __syncthreads();
#pragma unroll
        for (int ks = 0; ks < 64; ks += 32) {
            h8_t af[4], bf[4];
#pragma unroll
            for (int mt = 0; mt < 4; ++mt)
                af[mt] = *(const h8_t*)&As[wr * 64 + mt * 16 + fm][ks + fq * 8];
#pragma unroll
            for (int nt = 0; nt < 4; ++nt)
                bf[nt] = *(const h8_t*)&Bs[wc * 64 + nt * 16 + fm][ks + fq * 8];
#pragma unroll
            for (int mt = 0; mt < 4; ++mt)
#pragma unroll
                for (int nt = 0; nt < 4; ++nt)
                    acc[mt][nt] = __builtin_amdgcn_mfma_f32_16x16x32_f16(
                        af[mt], bf[nt], acc[mt][nt], 0, 0, 0);
        }
        __syncthreads();
    }
    // epilogue: C col = lane&15 (n-dim), row = (lane>>4)*4 + reg (m-dim)
#pragma unroll
    for (int nt = 0; nt < 4; ++nt) {
        int col = n0 + wc * 64 + nt * 16 + fm;
        int d = (col < 768) ? 0 : 1;
        int j = col - d * 768;
        float bias = d ? bihr[j] : bihf[j];
        size_t obase = (size_t)d * CROWS * 768 + j;
#pragma unroll
        for (int mt = 0; mt < 4; ++mt) {
            int row = row0 + wr * 64 + mt * 16 + fq * 4;
#pragma unroll
            for (int rr = 0; rr < 4; ++rr)
                xg[obase + (size_t)(row + rr) * 768] = (_Float16)(acc[mt][nt][rr] + bias);
        }
    }
}

// ---------------- persistent GRU scan chunk: 1 block per (direction, batch) chain ----------------
// 512 threads: thread (i=tid&255, half=tid>>8) computes partial dots of rows
// {i,i+256,i+512} over h[half*128 .. half*128+128). Weights: 192 VGPRs fp16.
// half=1 partials -> LDS; half=0 combines, computes gates, writes hbuf.
// lds_pad (80 KB, kept alive via runtime-false write) forces 1 block/CU so
// the register allocator budgets 256 VGPRs instead of 128 (see header note).
__global__ __launch_bounds__(512)
void scan_kernel(const _Float16* __restrict__ xg,
                 const float* __restrict__ whhf, const float* __restrict__ whhr,
                 const float* __restrict__ bhhf, const float* __restrict__ bhhr,
                 const float* __restrict__ clf_w, float* __restrict__ psum,
                 float* __restrict__ hstate, int t0, int len, int first) {
    int blk = blockIdx.x;
    int d = blk >> 6, b = blk & 63;
    int tid = threadIdx.x;
    int i = tid & 255, half = tid >> 8;     // wave-uniform: waves 0-3 half=0, 4-7 half=1
    const float* whh = d ? whhr : whhf;
    const float* bhh = d ? bhhr : bhhf;

    __shared__ __align__(16) _Float16 hbuf[2][256];
    __shared__ float parr[3][256];
    __shared__ float lds_pad[20000];        // 80 KB occupancy limiter
    if (len == -1) lds_pad[tid] = (float)first;   // never true; keeps pad allocated

    const float* w0p = whh + (size_t)i * 256 + half * 128;
    const float* w1p = whh + (size_t)(i + 256) * 256 + half * 128;
    const float* w2p = whh + (size_t)(i + 512) * 256 + half * 128;
    h2_t w0[64], w1[64], w2[64];
#pragma unroll
    for (int c = 0; c < 32; ++c) {
        float4 f0 = *(const float4*)(w0p + c * 4);
        float4 f1 = *(const float4*)(w1p + c * 4);
        float4 f2 = *(const float4*)(w2p + c * 4);
        w0[2 * c]     = (h2_t){(_Float16)f0.x, (_Float16)f0.y};
        w0[2 * c + 1] = (h2_t){(_Float16)f0.z, (_Float16)f0.w};
        w1[2 * c]     = (h2_t){(_Float16)f1.x, (_Float16)f1.y};
        w1[2 * c + 1] = (h2_t){(_Float16)f1.z, (_Float16)f1.w};
        w2[2 * c]     = (h2_t){(_Float16)f2.x, (_Float16)f2.y};
        w2[2 * c + 1] = (h2_t){(_Float16)f2.z, (_Float16)f2.w};
    }
    float bhr = 0.f, bhz = 0.f, bhn = 0.f, cw0 = 0.f, cw1 = 0.f, h = 0.f;
    if (half == 0) {
        bhr = bhh[i]; bhz = bhh[256 + i]; bhn = bhh[512 + i];
        cw0 = clf_w[d * 256 + i];          // clf_w[0][d*256+i]
        cw1 = clf_w[512 + d * 256 + i];    // clf_w[1][d*256+i]
        h = first ? 0.f : hstate[(size_t)blk * 256 + i];
    }

    if (half == 0) hbuf[0][i] = (_Float16)h;
    __syncthreads();

    const _Float16* xgp = xg + (size_t)d * CROWS * 768 + (size_t)b * 768 + i;
    int cur = 0;
    for (int t = 0; t < len; ++t) {
        float xr = 0.f, xz = 0.f, xn = 0.f;
        if (half == 0) {
            xr = (float)xgp[0];
            xz = (float)xgp[256];
            xn = (float)xgp[512];
        }
        xgp += (size_t)64 * 768;

        const uint4* hp = (const uint4*)&hbuf[cur][half * 128];
        float a0 = 0.f, a1 = 0.f, a2 = 0.f, s0 = 0.f, s1 = 0.f, s2 = 0.f;
        // 8 iterations x 2 uint4 = 16 uint4 = 128 fp16 = this thread's h slice;
        // w index cc*8+p spans 0..63 h2 = the 128-wide weight slice.
#pragma unroll
        for (int cc = 0; cc < 8; ++cc) {
            uint4 qa = hp[cc * 2 + 0];
            uint4 qb = hp[cc * 2 + 1];
            h2_t ha0 = __builtin_bit_cast(h2_t, qa.x), ha1 = __builtin_bit_cast(h2_t, qa.y);
            h2_t ha2 = __builtin_bit_cast(h2_t, qa.z), ha3 = __builtin_bit_cast(h2_t, qa.w);
            h2_t hb0 = __builtin_bit_cast(h2_t, qb.x), hb1 = __builtin_bit_cast(h2_t, qb.y);
            h2_t hb2 = __builtin_bit_cast(h2_t, qb.z), hb3 = __builtin_bit_cast(h2_t, qb.w);
            a0 = __builtin_amdgcn_fdot2(w0[cc * 8 + 0], ha0, a0, false);
            a1 = __builtin_amdgcn_fdot2(w1[cc * 8 + 0], ha0, a1, false);
            a2 = __builtin_amdgcn_fdot2(w2[cc * 8 + 0], ha0, a2, false);
            s0 = __builtin_amdgcn_fdot2(w0[cc * 8 + 4], hb0, s0, false);
            s1 = __builtin_amdgcn_fdot2(w1[cc * 8 + 4], hb0, s1, false);
            s2 = __builtin_amdgcn_fdot2(w2[cc * 8 + 4], hb0, s2, false);
            a0 = __builtin_amdgcn_fdot2(w0[cc * 8 + 1], ha1, a0, false);
            a1 = __builtin_amdgcn_fdot2(w1[cc * 8 + 1], ha1, a1, false);
            a2 = __builtin_amdgcn_fdot2(w2[cc * 8 + 1], ha1, a2, false);
            s0 = __builtin_amdgcn_fdot2(w0[cc * 8 + 5], hb1, s0, false);
            s1 = __builtin_amdgcn_fdot2(w1[cc * 8 + 5], hb1, s1, false);
            s2 = __builtin_amdgcn_fdot2(w2[cc * 8 + 5], hb1, s2, false);
            a0 = __builtin_amdgcn_fdot2(w0[cc * 8 + 2], ha2, a0, false);
            a1 = __builtin_amdgcn_fdot2(w1[cc * 8 + 2], ha2, a1, false);
            a2 = __builtin_amdgcn_fdot2(w2[cc * 8 + 2], ha2, a2, false);
            s0 = __builtin_amdgcn_fdot2(w0[cc * 8 + 6], hb2, s0, false);
            s1 = __builtin_amdgcn_fdot2(w1[cc * 8 + 6], hb2, s1, false);
            s2 = __builtin_amdgcn_fdot2(w2[cc * 8 + 6], hb2, s2, false);
            a0 = __builtin_amdgcn_fdot2(w0[cc * 8 + 3], ha3, a0, false);
            a1 = __builtin_amdgcn_fdot2(w1[cc * 8 + 3], ha3, a1, false);
            a2 = __builtin_amdgcn_fdot2(w2[cc * 8 + 3], ha3, a2, false);
            s0 = __builtin_amdgcn_fdot2(w0[cc * 8 + 7], hb3, s0, false);
            s1 = __builtin_amdgcn_fdot2(w1[cc * 8 + 7], hb3, s1, false);
            s2 = __builtin_amdgcn_fdot2(w2[cc * 8 + 7], hb3, s2, false);
        }
        float p0 = a0 + s0, p1 = a1 + s1, p2 = a2 + s2;
        if (half == 1) {
            parr[0][i] = p0; parr[1][i] = p1; parr[2][i] = p2;
        }
        __syncthreads();
        if (half == 0) {
            float hr = p0 + parr[0][i] + bhr;
            float hz = p1 + parr[1][i] + bhz;
            float hn = p2 + parr[2][i] + bhn;
            float rg = 1.f / (1.f + __expf(-(xr + hr)));
            float zg = 1.f / (1.f + __expf(-(xz + hz)));
            float xnr = xn + rg * hn;
            float nv = 1.f - 2.f / (__expf(2.f * xnr) + 1.f);   // tanh
            h = (1.f - zg) * nv + zg * h;
            hbuf[cur ^ 1][i] = (_Float16)h;

            float pc0 = cw0 * h, pc1 = cw1 * h;
#pragma unroll
            for (int off = 32; off; off >>= 1) {
                pc0 += __shfl_xor(pc0, off, 64);
                pc1 += __shfl_xor(pc1, off, 64);
            }
            if ((tid & 63) == 0) {
                atomicAdd(&psum[((size_t)(t0 + t) * 64 + b) * 2 + 0], pc0);
                atomicAdd(&psum[((size_t)(t0 + t) * 64 + b) * 2 + 1], pc1);
            }
        }
        __syncthreads();
        cur ^= 1;
    }
    if (half == 0) hstate[(size_t)blk * 256 + i] = h;
}

// ---------------- final: sliding mean over W steps + clf bias ----------------
__global__ void final_kernel(const float* __restrict__ psum, const float* __restrict__ clf_b,
                             const int* __restrict__ win, float* __restrict__ out) {
    int idx = blockIdx.x * 256 + threadIdx.x;
    if (idx >= TOUT * 128) return;
    int c = idx & 1;
    int rem = idx >> 1;
    int b = rem & 63;
    int tau = rem >> 6;
    int W = win[0] - 5 + 1;   // 96
    float s = 0.f;
    for (int j = 0; j < W; ++j)
        s += psum[((size_t)(tau + j) * 64 + b) * 2 + c];
    out[idx] = s / (float)W + clf_b[c];
}

extern "C" void kernel_launch(void* const* d_in, const int* in_sizes, int n_in,
                              void* d_out, int out_size, void* d_ws, size_t ws_size,
                              hipStream_t stream) {
    const float* x      = (const float*)d_in[0];
    const float* conv_w = (const float*)d_in[1];
    const float* conv_b = (const float*)d_in[2];
    const float* w_ih_f = (const float*)d_in[3];
    const float* w_hh_f = (const float*)d_in[4];
    const float* b_ih_f = (const float*)d_in[5];
    const float* b_hh_f = (const float*)d_in[6];
    const float* w_ih_r = (const float*)d_in[7];
    const float* w_hh_r = (const float*)d_in[8];
    const float* b_ih_r = (const float*)d_in[9];
    const float* b_hh_r = (const float*)d_in[10];
    const float* clf_w  = (const float*)d_in[11];
    const float* clf_b  = (const float*)d_in[12];
    const int*   win    = (const int*)d_in[13];
    float* out = (float*)d_out;

    char* ws = (char*)d_ws;
    _Float16* seqc = (_Float16*)(ws + OFF_SEQC);
    _Float16* xg   = (_Float16*)(ws + OFF_XG);
    float*    wT   = (float*)(ws + OFF_WT);
    _Float16* wcat = (_Float16*)(ws + OFF_WCAT);
    float*    psum = (float*)(ws + OFF_PSUM);
    float*    hst  = (float*)(ws + OFF_HST);

    int prep_elems = 400 * 256 + NN * 256 + TC * 64 * 2;
    prep_kernel<<<(prep_elems + 255) / 256, 256, 0, stream>>>(conv_w, w_ih_f, w_ih_r, wT, wcat, psum);

    for (int c = 0; c < NCHK; ++c) {
        int t0  = c * TCH;
        int len = (c == NCHK - 1) ? (TC - t0) : TCH;   // 250 / last 246
        conv_kernel<<<dim3(4, 64), 256, 0, stream>>>(x, wT, conv_b, seqc, t0, len);
        proj_kernel<<<dim3(len * 64 / 128, 12), 256, 0, stream>>>(seqc, wcat, b_ih_f, b_ih_r, xg);
        scan_kernel<<<128, 512, 0, stream>>>(xg, w_hh_f, w_hh_r, b_hh_f, b_hh_r,
                                             clf_w, psum, hst, t0, len, c == 0);
    }
    final_kernel<<<(TOUT * 128 + 255) / 256, 256, 0, stream>>>(psum, clf_b, win, out);
}

// Round 9
// 4335.276 us; speedup vs baseline: 1.1407x; 1.0042x over previous
//
#include <hip/hip_runtime.h>
#include <hip/hip_bf16.h>

// KWSNet: conv1d+relu -> 2x GRU (fwd-scan, two weight sets) -> sliding mean -> linear(2)
// B=64, M=80, T=2000, C=H=256, K=5; Tc=1996, W=96, Tout=1901, out (1901,1,64,2) fp32.
//
// Chunked pipeline (8 x <=250 steps), per chunk: conv -> proj (fp16 MFMA) ->
// persistent GRU scan. Scan: 512 threads/block, thread (i=tid&255, half=tid>>8)
// holds W_hh rows {i,i+256,i+512} cols [half*128,half*128+128) in 192 VGPRs.
//
// Register-budget law measured R3-R8: backend targets 2 blocks/CU and budgets
// 65536/B VGPRs (B=threads/block) -- the fp16 W_hh (98304 slots/block) never
// fits, spilling 44 MB to scratch; spill reloads (393 KB/CU/step from L2)
// explain the 435us scan. Fix: 80 KB LDS pad forces 1 block/CU at COMPILE
// time -> budget 256 VGPRs. R8's pad was DCE'd (dead store); now kept alive
// by a runtime-false branch with write -> barrier -> dependent global store.

#define TT    2000
#define TC    1996
#define NB    64
#define MCH   80
#define NH    256
#define NN    1536           // 2 * 3H
#define TOUT  1901
#define TCH   250            // chunk length (last chunk = 246)
#define NCHK  8
#define CROWS (TCH * NB)     // 16000 rows per chunk

typedef _Float16 h2_t __attribute__((ext_vector_type(2)));
typedef _Float16 h8_t __attribute__((ext_vector_type(8)));
typedef float    f4_t __attribute__((ext_vector_type(4)));

// ---------------- workspace layout (bytes), total ~59.7 MB ----------------
#define OFF_SEQC ((size_t)0)            // fp16 [CROWS][256]     = 8,192,000
#define OFF_XG   ((size_t)8192000)      // fp16 [2][CROWS][768]  = 49,152,000
#define OFF_WT   ((size_t)57344000)     // fp32 [400][256]       = 409,600
#define OFF_WCAT ((size_t)57753600)     // fp16 [1536][256]      = 786,432
#define OFF_PSUM ((size_t)58540032)     // fp32 [TC][64][2]      = 1,021,952
#define OFF_HST  ((size_t)59561984)     // fp32 [128][256]       = 131,072

// ---------------- prep: transpose conv_w, fp16 w_ih concat, zero psum ----------------
__global__ void prep_kernel(const float* __restrict__ conv_w,
                            const float* __restrict__ wihf,
                            const float* __restrict__ wihr,
                            float* __restrict__ wT,
                            _Float16* __restrict__ wcat,
                            float* __restrict__ psum) {
    int idx = blockIdx.x * 256 + threadIdx.x;
    if (idx < 400 * 256) {
        int c = idx & 255, mk = idx >> 8;
        wT[idx] = conv_w[c * 400 + mk];
    }
    int i2 = idx - 400 * 256;
    if (i2 >= 0 && i2 < NN * 256) {
        int k = i2 & 255, n = i2 >> 8;
        float v = (n < 768) ? wihf[n * 256 + k] : wihr[(n - 768) * 256 + k];
        wcat[i2] = (_Float16)v;
    }
    int i3 = idx - (400 * 256 + NN * 256);
    if (i3 >= 0 && i3 < TC * 64 * 2) psum[i3] = 0.f;
}

// ---------------- conv1d(valid,K=5)+bias+relu -> seqc fp16 [t_local*64+b][c] ----------------
__global__ __launch_bounds__(256, 2)
void conv_kernel(const float* __restrict__ x, const float* __restrict__ wT,
                 const float* __restrict__ conv_b, _Float16* __restrict__ seqc,
                 int t_base, int t_len) {
    __shared__ float xs[MCH][68];
    int tile = blockIdx.x;           // 0..3
    int b    = blockIdx.y;           // 0..63
    int tid  = threadIdx.x;
    for (int idx = tid; idx < MCH * 68; idx += 256) {
        int m = idx / 68, i = idx - m * 68;
        int tt = t_base + tile * 64 + i;
        xs[m][i] = (tt < TT) ? x[(size_t)b * (MCH * TT) + m * TT + tt] : 0.f;
    }
    __syncthreads();
    int lane = tid & 63, tg = tid >> 6;   // wave tg: t-range [tg*16, tg*16+16)
    float acc[4][16];
#pragma unroll
    for (int cq = 0; cq < 4; ++cq)
#pragma unroll
        for (int t = 0; t < 16; ++t) acc[cq][t] = 0.f;

    for (int m = 0; m < MCH; ++m) {
        float xr_[20];
#pragma unroll
        for (int q = 0; q < 5; ++q) {
            float4 v = *(const float4*)&xs[m][tg * 16 + q * 4];
            xr_[q * 4 + 0] = v.x; xr_[q * 4 + 1] = v.y;
            xr_[q * 4 + 2] = v.z; xr_[q * 4 + 3] = v.w;
        }
#pragma unroll
        for (int cq = 0; cq < 4; ++cq) {
            int c = lane + cq * 64;
            const float* wp = wT + (size_t)(m * 5) * 256 + c;
            float w0_ = wp[0], w1_ = wp[256], w2_ = wp[512], w3_ = wp[768], w4_ = wp[1024];
#pragma unroll
            for (int t = 0; t < 16; ++t)
                acc[cq][t] += w0_ * xr_[t] + w1_ * xr_[t + 1] + w2_ * xr_[t + 2]
                            + w3_ * xr_[t + 3] + w4_ * xr_[t + 4];
        }
    }
#pragma unroll
    for (int cq = 0; cq < 4; ++cq) {
        int c = lane + cq * 64;
        float cb = conv_b[c];
        for (int t = 0; t < 16; ++t) {
            int tl = tile * 64 + tg * 16 + t;     // t within chunk
            if (tl < t_len) {
                float v = acc[cq][t] + cb;
                v = v > 0.f ? v : 0.f;
                seqc[((size_t)tl * 64 + b) * 256 + c] = (_Float16)v;
            }
        }
    }
}

// ---------------- proj: xg[d][row][j] = seqc @ w_ih^T + b_ih (fp16 MFMA 16x16x32) ----------------
__global__ __launch_bounds__(256, 2)
void proj_kernel(const _Float16* __restrict__ seqc, const _Float16* __restrict__ wcat,
                 const float* __restrict__ bihf, const float* __restrict__ bihr,
                 _Float16* __restrict__ xg) {
    __shared__ __align__(16) _Float16 As[128][72];
    __shared__ __align__(16) _Float16 Bs[128][72];
    int row0 = blockIdx.x * 128;     // up to 125 tiles
    int n0   = blockIdx.y * 128;     // 12 tiles
    int tid  = threadIdx.x;
    int lane = tid & 63, wv = tid >> 6;
    int wr = wv >> 1, wc = wv & 1;                 // 2x2 waves of 64x64
    int fm = lane & 15, fq = lane >> 4;            // fragment index, quad
    f4_t acc[4][4];
#pragma unroll
    for (int mt = 0; mt < 4; ++mt)
#pragma unroll
        for (int nt = 0; nt < 4; ++nt) acc[mt][nt] = (f4_t){0.f, 0.f, 0.f, 0.f};

    int r = tid >> 1, part = tid & 1;
    for (int kc = 0; kc < 4; ++kc) {
        const uint4* srcA = (const uint4*)&seqc[(size_t)(row0 + r) * 256 + kc * 64 + part * 32];
        const uint4* srcB = (const uint4*)&wcat[(size_t)(n0 + r) * 256 + kc * 64 + part * 32];
        uint4* dstA = (uint4*)&As[r][part * 32];
        uint4* dstB = (uint4*)&Bs[r][part * 32];
        dstA[0] = srcA[0]; dstA[1] = srcA[1]; dstA[2] = srcA[2]; dstA[3] = srcA[3];
        dstB[0] = srcB[0]; dstB[1] = srcB[1]; dstB[2] = srcB[2]; dstB[3] = srcB[3];
        __syncthreads();
#pragma unroll
        for (int ks = 0; ks < 64; ks += 32) {
            h8_t af[4], bf[4];
#pragma unroll
            for (int mt = 0; mt < 4; ++mt)
                af[mt] = *(const h8_t*)&As[wr * 64 + mt * 16 + fm][ks + fq * 8];
#pragma unroll
            for (int nt = 0; nt < 4; ++nt)
                bf[nt] = *(const h8_t*)&Bs[wc * 64 + nt * 16 + fm][ks + fq * 8];
#pragma unroll
            for (int mt = 0; mt < 4; ++mt)
#pragma unroll
                for (int nt = 0; nt < 4; ++nt)
                    acc[mt][nt] = __builtin_amdgcn_mfma_f32_16x16x32_f16(
                        af[mt], bf[nt], acc[mt][nt], 0, 0, 0);
        }
        __syncthreads();
    }
    // epilogue: C col = lane&15 (n-dim), row = (lane>>4)*4 + reg (m-dim)
#pragma unroll
    for (int nt = 0; nt < 4; ++nt) {
        int col = n0 + wc * 64 + nt * 16 + fm;
        int d = (col < 768) ? 0 : 1;
        int j = col - d * 768;
        float bias = d ? bihr[j] : bihf[j];
        size_t obase = (size_t)d * CROWS * 768 + j;
#pragma unroll
        for (int mt = 0; mt < 4; ++mt) {
            int row = row0 + wr * 64 + mt * 16 + fq * 4;
#pragma unroll
            for (int rr = 0; rr < 4; ++rr)
                xg[obase + (size_t)(row + rr) * 768] = (_Float16)(acc[mt][nt][rr] + bias);
        }
    }
}

// ---------------- persistent GRU scan chunk: 1 block per (direction, batch) chain ----------------
// 512 threads: thread (i=tid&255, half=tid>>8) computes partial dots of rows
// {i,i+256,i+512} over h[half*128 .. half*128+128). Weights: 192 VGPRs fp16.
// half=1 partials -> LDS; half=0 combines, computes gates, writes hbuf.
// lds_pad (80 KB) limits compile-time occupancy to 1 block/CU so the register
// allocator budgets 256 VGPRs. The pad is kept alive by a runtime-false branch
// (len<0 never holds) whose global store depends on values read from the pad
// across a barrier -- not removable by DSE/DCE (R8's plain dead store was).
__global__ __launch_bounds__(512)
void scan_kernel(const _Float16* __restrict__ xg,
                 const float* __restrict__ whhf, const float* __restrict__ whhr,
                 const float* __restrict__ bhhf, const float* __restrict__ bhhr,
                 const float* __restrict__ clf_w, float* __restrict__ psum,
                 float* __restrict__ hstate, int t0, int len, int first) {
    int blk = blockIdx.x;
    int d = blk >> 6, b = blk & 63;
    int tid = threadIdx.x;
    int i = tid & 255, half = tid >> 8;     // wave-uniform: waves 0-3 half=0, 4-7 half=1
    const float* whh = d ? whhr : whhf;
    const float* bhh = d ? bhhr : bhhf;

    __shared__ __align__(16) _Float16 hbuf[2][256];
    __shared__ float parr[3][256];
    __shared__ float lds_pad[20480];        // 80 KB occupancy limiter
    if (__builtin_expect(len < 0, 0)) {     // never true at runtime
        lds_pad[tid] = (float)first;
        lds_pad[512 + ((tid * 37) & 16383)] = (float)tid;
        __syncthreads();
        hstate[tid] = lds_pad[511 - tid] + lds_pad[512 + ((tid * 131) & 16383)];
        return;
    }

    const float* w0p = whh + (size_t)i * 256 + half * 128;
    const float* w1p = whh + (size_t)(i + 256) * 256 + half * 128;
    const float* w2p = whh + (size_t)(i + 512) * 256 + half * 128;
    h2_t w0[64], w1[64], w2[64];
#pragma unroll
    for (int c = 0; c < 32; ++c) {
        float4 f0 = *(const float4*)(w0p + c * 4);
        float4 f1 = *(const float4*)(w1p + c * 4);
        float4 f2 = *(const float4*)(w2p + c * 4);
        w0[2 * c]     = (h2_t){(_Float16)f0.x, (_Float16)f0.y};
        w0[2 * c + 1] = (h2_t){(_Float16)f0.z, (_Float16)f0.w};
        w1[2 * c]     = (h2_t){(_Float16)f1.x, (_Float16)f1.y};
        w1[2 * c + 1] = (h2_t){(_Float16)f1.z, (_Float16)f1.w};
        w2[2 * c]     = (h2_t){(_Float16)f2.x, (_Float16)f2.y};
        w2[2 * c + 1] = (h2_t){(_Float16)f2.z, (_Float16)f2.w};
    }
    float bhr = 0.f, bhz = 0.f, bhn = 0.f, cw0 = 0.f, cw1 = 0.f, h = 0.f;
    if (half == 0) {
        bhr = bhh[i]; bhz = bhh[256 + i]; bhn = bhh[512 + i];
        cw0 = clf_w[d * 256 + i];          // clf_w[0][d*256+i]
        cw1 = clf_w[512 + d * 256 + i];    // clf_w[1][d*256+i]
        h = first ? 0.f : hstate[(size_t)blk * 256 + i];
    }

    if (half == 0) hbuf[0][i] = (_Float16)h;
    __syncthreads();

    const _Float16* xgp = xg + (size_t)d * CROWS * 768 + (size_t)b * 768 + i;
    int cur = 0;
    for (int t = 0; t < len; ++t) {
        float xr = 0.f, xz = 0.f, xn = 0.f;
        if (half == 0) {
            xr = (float)xgp[0];
            xz = (float)xgp[256];
            xn = (float)xgp[512];
        }
        xgp += (size_t)64 * 768;

        const uint4* hp = (const uint4*)&hbuf[cur][half * 128];
        float a0 = 0.f, a1 = 0.f, a2 = 0.f, s0 = 0.f, s1 = 0.f, s2 = 0.f;
        // 8 iterations x 2 uint4 = 16 uint4 = 128 fp16 = this thread's h slice;
        // w index cc*8+p spans 0..63 h2 = the 128-wide weight slice.
#pragma unroll
        for (int cc = 0; cc < 8; ++cc) {
            uint4 qa = hp[cc * 2 + 0];
            uint4 qb = hp[cc * 2 + 1];
            h2_t ha0 = __builtin_bit_cast(h2_t, qa.x), ha1 = __builtin_bit_cast(h2_t, qa.y);
            h2_t ha2 = __builtin_bit_cast(h2_t, qa.z), ha3 = __builtin_bit_cast(h2_t, qa.w);
            h2_t hb0 = __builtin_bit_cast(h2_t, qb.x), hb1 = __builtin_bit_cast(h2_t, qb.y);
            h2_t hb2 = __builtin_bit_cast(h2_t, qb.z), hb3 = __builtin_bit_cast(h2_t, qb.w);
            a0 = __builtin_amdgcn_fdot2(w0[cc * 8 + 0], ha0, a0, false);
            a1 = __builtin_amdgcn_fdot2(w1[cc * 8 + 0], ha0, a1, false);
            a2 = __builtin_amdgcn_fdot2(w2[cc * 8 + 0], ha0, a2, false);
            s0 = __builtin_amdgcn_fdot2(w0[cc * 8 + 4], hb0, s0, false);
            s1 = __builtin_amdgcn_fdot2(w1[cc * 8 + 4], hb0, s1, false);
            s2 = __builtin_amdgcn_fdot2(w2[cc * 8 + 4], hb0, s2, false);
            a0 = __builtin_amdgcn_fdot2(w0[cc * 8 + 1], ha1, a0, false);
            a1 = __builtin_amdgcn_fdot2(w1[cc * 8 + 1], ha1, a1, false);
            a2 = __builtin_amdgcn_fdot2(w2[cc * 8 + 1], ha1, a2, false);
            s0 = __builtin_amdgcn_fdot2(w0[cc * 8 + 5], hb1, s0, false);
            s1 = __builtin_amdgcn_fdot2(w1[cc * 8 + 5], hb1, s1, false);
            s2 = __builtin_amdgcn_fdot2(w2[cc * 8 + 5], hb1, s2, false);
            a0 = __builtin_amdgcn_fdot2(w0[cc * 8 + 2], ha2, a0, false);
            a1 = __builtin_amdgcn_fdot2(w1[cc * 8 + 2], ha2, a1, false);
            a2 = __builtin_amdgcn_fdot2(w2[cc * 8 + 2], ha2, a2, false);
            s0 = __builtin_amdgcn_fdot2(w0[cc * 8 + 6], hb2, s0, false);
            s1 = __builtin_amdgcn_fdot2(w1[cc * 8 + 6], hb2, s1, false);
            s2 = __builtin_amdgcn_fdot2(w2[cc * 8 + 6], hb2, s2, false);
            a0 = __builtin_amdgcn_fdot2(w0[cc * 8 + 3], ha3, a0, false);
            a1 = __builtin_amdgcn_fdot2(w1[cc * 8 + 3], ha3, a1, false);
            a2 = __builtin_amdgcn_fdot2(w2[cc * 8 + 3], ha3, a2, false);
            s0 = __builtin_amdgcn_fdot2(w0[cc * 8 + 7], hb3, s0, false);
            s1 = __builtin_amdgcn_fdot2(w1[cc * 8 + 7], hb3, s1, false);
            s2 = __builtin_amdgcn_fdot2(w2[cc * 8 + 7], hb3, s2, false);
        }
        float p0 = a0 + s0, p1 = a1 + s1, p2 = a2 + s2;
        if (half == 1) {
            parr[0][i] = p0; parr[1][i] = p1; parr[2][i] = p2;
        }
        __syncthreads();
        if (half == 0) {
            float hr = p0 + parr[0][i] + bhr;
            float hz = p1 + parr[1][i] + bhz;
            float hn = p2 + parr[2][i] + bhn;
            float rg = 1.f / (1.f + __expf(-(xr + hr)));
            float zg = 1.f / (1.f + __expf(-(xz + hz)));
            float xnr = xn + rg * hn;
            float nv = 1.f - 2.f / (__expf(2.f * xnr) + 1.f);   // tanh
            h = (1.f - zg) * nv + zg * h;
            hbuf[cur ^ 1][i] = (_Float16)h;

            float pc0 = cw0 * h, pc1 = cw1 * h;
#pragma unroll
            for (int off = 32; off; off >>= 1) {
                pc0 += __shfl_xor(pc0, off, 64);
                pc1 += __shfl_xor(pc1, off, 64);
            }
            if ((tid & 63) == 0) {
                atomicAdd(&psum[((size_t)(t0 + t) * 64 + b) * 2 + 0], pc0);
                atomicAdd(&psum[((size_t)(t0 + t) * 64 + b) * 2 + 1], pc1);
            }
        }
        __syncthreads();
        cur ^= 1;
    }
    if (half == 0) hstate[(size_t)blk * 256 + i] = h;
}

// ---------------- final: sliding mean over W steps + clf bias ----------------
__global__ void final_kernel(const float* __restrict__ psum, const float* __restrict__ clf_b,
                             const int* __restrict__ win, float* __restrict__ out) {
    int idx = blockIdx.x * 256 + threadIdx.x;
    if (idx >= TOUT * 128) return;
    int c = idx & 1;
    int rem = idx >> 1;
    int b = rem & 63;
    int tau = rem >> 6;
    int W = win[0] - 5 + 1;   // 96
    float s = 0.f;
    for (int j = 0; j < W; ++j)
        s += psum[((size_t)(tau + j) * 64 + b) * 2 + c];
    out[idx] = s / (float)W + clf_b[c];
}

extern "C" void kernel_launch(void* const* d_in, const int* in_sizes, int n_in,
                              void* d_out, int out_size, void* d_ws, size_t ws_size,
                              hipStream_t stream) {
    const float* x      = (const float*)d_in[0];
    const float* conv_w = (const float*)d_in[1];
    const float* conv_b = (const float*)d_in[2];
    const float* w_ih_f = (const float*)d_in[3];
    const float* w_hh_f = (const float*)d_in[4];
    const float* b_ih_f = (const float*)d_in[5];
    const float* b_hh_f = (const float*)d_in[6];
    const float* w_ih_r = (const float*)d_in[7];
    const float* w_hh_r = (const float*)d_in[8];
    const float* b_ih_r = (const float*)d_in[9];
    const float* b_hh_r = (const float*)d_in[10];
    const float* clf_w  = (const float*)d_in[11];
    const float* clf_b  = (const float*)d_in[12];
    const int*   win    = (const int*)d_in[13];
    float* out = (float*)d_out;

    char* ws = (char*)d_ws;
    _Float16* seqc = (_Float16*)(ws + OFF_SEQC);
    _Float16* xg   = (_Float16*)(ws + OFF_XG);
    float*    wT   = (float*)(ws + OFF_WT);
    _Float16* wcat = (_Float16*)(ws + OFF_WCAT);
    float*    psum = (float*)(ws + OFF_PSUM);
    float*    hst  = (float*)(ws + OFF_HST);

    int prep_elems = 400 * 256 + NN * 256 + TC * 64 * 2;
    prep_kernel<<<(prep_elems + 255) / 256, 256, 0, stream>>>(conv_w, w_ih_f, w_ih_r, wT, wcat, psum);

    for (int c = 0; c < NCHK; ++c) {
        int t0  = c * TCH;
        int len = (c == NCHK - 1) ? (TC - t0) : TCH;   // 250 / last 246
        conv_kernel<<<dim3(4, 64), 256, 0, stream>>>(x, wT, conv_b, seqc, t0, len);
        proj_kernel<<<dim3(len * 64 / 128, 12), 256, 0, stream>>>(seqc, wcat, b_ih_f, b_ih_r, xg);
        scan_kernel<<<128, 512, 0, stream>>>(xg, w_hh_f, w_hh_r, b_hh_f, b_hh_r,
                                             clf_w, psum, hst, t0, len, c == 0);
    }
    final_kernel<<<(TOUT * 128 + 255) / 256, 256, 0, stream>>>(psum, clf_b, win, out);
}